// Round 1
// baseline (283.244 us; speedup 1.0000x reference)
//
#include <hip/hip_runtime.h>
#include <cstddef>

// Problem constants (from reference)
#define BB 64
#define NN 207
#define KK 32
#define CC 8
#define DIN 64
#define DOUT 64
#define TILE 8               // n-positions per block
#define NT ((NN + TILE - 1) / TILE)   // 26 tiles along N
#define MPAD 68              // mean row stride (64 + 4 pad -> 272 B, bank-offset 4)

__global__ __launch_bounds__(256) void ordered_gcn_kernel(
    const int* __restrict__ idx,      // [B, N, K]
    const float* __restrict__ x,      // [B, N, K, DIN]
    const float* __restrict__ W,      // [C, DOUT, DIN]
    float* __restrict__ out)          // [B, N, C, DOUT]
{
    __shared__ int   idx_s[TILE * KK];          // 256 ints
    __shared__ float inv_s[TILE * CC];          // 64 floats
    __shared__ float mean_s[TILE * CC * MPAD];  // 8*8*68*4 = 17408 B

    const int tid = threadIdx.x;
    const int b  = blockIdx.y;
    const int n0 = blockIdx.x * TILE;

    // ---- load idx tile: one int per thread, coalesced ----
    {
        const int p = tid >> 5;      // pos 0..7
        const int k = tid & 31;
        const int n = n0 + p;
        idx_s[tid] = (n < NN) ? idx[((size_t)(b * NN + n)) * KK + k] : 0;
    }
    __syncthreads();

    // ---- per (pos, class) inverse clamped count ----
    if (tid < TILE * CC) {
        const int p = tid >> 3, c = tid & 7;
        int cnt = 0;
        #pragma unroll
        for (int k = 0; k < KK; ++k) cnt += (idx_s[p * KK + k] == c) ? 1 : 0;
        inv_s[tid] = 1.0f / (float)(cnt > 1 ? cnt : 1);
    }
    __syncthreads();

    // ---- phase 1: class-bucketed sums -> mean_s ----
    // thread = (pg = tid>>6 in 0..3, d = tid&63); each handles pos pg and pg+4.
    // wave reads contiguous 256 B rows of x -> fully coalesced.
    {
        const int d  = tid & 63;
        const int pg = tid >> 6;
        #pragma unroll
        for (int pp = 0; pp < 2; ++pp) {
            const int p = pg + pp * 4;
            const int n = n0 + p;
            float acc[CC];
            #pragma unroll
            for (int c = 0; c < CC; ++c) acc[c] = 0.0f;
            if (n < NN) {
                const float* xp = x + ((size_t)(b * NN + n)) * KK * DIN + d;
                #pragma unroll
                for (int k = 0; k < KK; ++k) {
                    const int   c = idx_s[p * KK + k];   // LDS broadcast (wave-uniform)
                    const float v = xp[(size_t)k * DIN];
                    #pragma unroll
                    for (int cc = 0; cc < CC; ++cc)
                        acc[cc] += (c == cc) ? v : 0.0f;
                }
            }
            #pragma unroll
            for (int cc = 0; cc < CC; ++cc)
                mean_s[(p * CC + cc) * MPAD + d] = acc[cc] * inv_s[p * CC + cc];
        }
    }
    __syncthreads();

    // ---- phase 2: out[p][c][o] = tanh(sum_d mean[p][c][d] * W[c][o][d]) ----
    // thread = (ph = tid>>7, c = (tid>>4)&7, o0 = (tid&15)*4); register tile acc[4 pos][4 o].
    {
        const int ph = tid >> 7;            // pos half: 0 -> pos 0..3, 1 -> pos 4..7
        const int c  = (tid >> 4) & 7;
        const int o0 = (tid & 15) * 4;
        float acc[4][4];
        #pragma unroll
        for (int pp = 0; pp < 4; ++pp)
            #pragma unroll
            for (int j = 0; j < 4; ++j) acc[pp][j] = 0.0f;

        const float* Wc = W + (size_t)c * DOUT * DIN;
        #pragma unroll
        for (int dd = 0; dd < DIN; dd += 4) {
            float4 w[4];
            #pragma unroll
            for (int j = 0; j < 4; ++j)
                w[j] = *(const float4*)(Wc + (size_t)(o0 + j) * DIN + dd);
            #pragma unroll
            for (int pp = 0; pp < 4; ++pp) {
                const int p = ph * 4 + pp;
                const float4 m = *(const float4*)(&mean_s[(p * CC + c) * MPAD + dd]);
                #pragma unroll
                for (int j = 0; j < 4; ++j) {
                    acc[pp][j] = fmaf(m.x, w[j].x, acc[pp][j]);
                    acc[pp][j] = fmaf(m.y, w[j].y, acc[pp][j]);
                    acc[pp][j] = fmaf(m.z, w[j].z, acc[pp][j]);
                    acc[pp][j] = fmaf(m.w, w[j].w, acc[pp][j]);
                }
            }
        }

        #pragma unroll
        for (int pp = 0; pp < 4; ++pp) {
            const int p = ph * 4 + pp;
            const int n = n0 + p;
            if (n < NN) {
                float4 r;
                r.x = tanhf(acc[pp][0]);
                r.y = tanhf(acc[pp][1]);
                r.z = tanhf(acc[pp][2]);
                r.w = tanhf(acc[pp][3]);
                *(float4*)(out + (((size_t)(b * NN + n)) * CC + c) * DOUT + o0) = r;
            }
        }
    }
}

extern "C" void kernel_launch(void* const* d_in, const int* in_sizes, int n_in,
                              void* d_out, int out_size, void* d_ws, size_t ws_size,
                              hipStream_t stream) {
    const int*   idx = (const int*)d_in[0];    // clustered_index_topk [B,N,K] int32
    const float* x   = (const float*)d_in[1];  // weightedDinput_topk [B,N,K,DIN] f32
    const float* W   = (const float*)d_in[2];  // W [C,DOUT,DIN] f32
    float* out = (float*)d_out;                // [B,N,C,DOUT] f32

    dim3 grid(NT, BB);   // 26 x 64 = 1664 blocks
    dim3 block(256);
    ordered_gcn_kernel<<<grid, block, 0, stream>>>(idx, x, W, out);
}

// Round 2
// 244.060 us; speedup vs baseline: 1.1606x; 1.1606x over previous
//
#include <hip/hip_runtime.h>
#include <cstddef>

// Problem constants (from reference)
#define BB 64
#define NN 207
#define KK 32
#define CC 8
#define DIN 64
#define DOUT 64
#define TILE 8               // n-positions per block
#define NT ((NN + TILE - 1) / TILE)   // 26 tiles along N
#define MPAD 68              // mean row stride (64 + 4 pad -> phase-2 c-rows land on distinct banks)

__device__ __forceinline__ float fast_tanh(float v) {
    // tanh(v) = 1 - 2/(exp(2v)+1); exact at +-inf saturation, ~1e-6 rel err.
    float e = __expf(2.0f * v);
    return 1.0f - 2.0f * __builtin_amdgcn_rcpf(e + 1.0f);
}

__global__ __launch_bounds__(256, 4) void ordered_gcn_kernel(
    const int* __restrict__ idx,      // [B, N, K]
    const float* __restrict__ x,      // [B, N, K, DIN]
    const float* __restrict__ W,      // [C, DOUT, DIN]
    float* __restrict__ out)          // [B, N, C, DOUT]
{
    __shared__ int   idx_s[TILE * KK];          // 256 ints
    __shared__ float inv_s[TILE * CC];          // 64 floats
    __shared__ float mean_s[TILE * CC * MPAD];  // 8*8*68*4 = 17408 B

    const int tid = threadIdx.x;
    const int b  = blockIdx.y;
    const int n0 = blockIdx.x * TILE;

    // ---- load idx tile: one int per thread, coalesced ----
    {
        const int p = tid >> 5;      // pos 0..7
        const int k = tid & 31;
        const int n = n0 + p;
        idx_s[tid] = (n < NN) ? idx[((size_t)(b * NN + n)) * KK + k] : 0;
    }
    __syncthreads();

    // ---- per (pos, class) inverse clamped count ----
    if (tid < TILE * CC) {
        const int p = tid >> 3, c = tid & 7;
        int cnt = 0;
        #pragma unroll
        for (int k = 0; k < KK; ++k) cnt += (idx_s[p * KK + k] == c) ? 1 : 0;
        inv_s[tid] = 1.0f / (float)(cnt > 1 ? cnt : 1);
    }
    __syncthreads();

    // ---- phase 1: class-bucketed sums -> mean_s ----
    // thread = (pg = tid>>6 in 0..3, d = tid&63); handles pos pg and pg+4 in ONE
    // k-loop (2 independent loads/iter for ILP). Wave reads contiguous 256 B rows.
    // Out-of-range pos: clamp the row pointer (reads valid memory, result never
    // stored) -> no branch in the hot loop.
    {
        const int d  = tid & 63;
        const int pg = tid >> 6;
        const int pa = pg, pb = pg + 4;
        int na = n0 + pa; if (na > NN - 1) na = NN - 1;
        int nb = n0 + pb; if (nb > NN - 1) nb = NN - 1;
        const float* __restrict__ xa = x + ((size_t)(b * NN + na)) * KK * DIN + d;
        const float* __restrict__ xb = x + ((size_t)(b * NN + nb)) * KK * DIN + d;

        float acca[CC], accb[CC];
        #pragma unroll
        for (int c = 0; c < CC; ++c) { acca[c] = 0.0f; accb[c] = 0.0f; }

        #pragma unroll 4
        for (int k = 0; k < KK; ++k) {
            const float va = xa[(size_t)k * DIN];
            const float vb = xb[(size_t)k * DIN];
            const int   ca = idx_s[pa * KK + k];
            const int   cb = idx_s[pb * KK + k];
            #pragma unroll
            for (int cc = 0; cc < CC; ++cc) {
                acca[cc] += (ca == cc) ? va : 0.0f;
                accb[cc] += (cb == cc) ? vb : 0.0f;
            }
        }

        #pragma unroll
        for (int cc = 0; cc < CC; ++cc) {
            mean_s[(pa * CC + cc) * MPAD + d] = acca[cc] * inv_s[pa * CC + cc];
            mean_s[(pb * CC + cc) * MPAD + d] = accb[cc] * inv_s[pb * CC + cc];
        }
    }
    __syncthreads();

    // ---- phase 2: out[p][c][o] = tanh(sum_d mean[p][c][d] * W[c][o][d]) ----
    // thread = (ph = tid>>7, c = (tid>>4)&7, o0 = (tid&15)*4); register tile acc[4 pos][4 o].
    {
        const int ph = tid >> 7;            // pos half: 0 -> pos 0..3, 1 -> pos 4..7
        const int c  = (tid >> 4) & 7;
        const int o0 = (tid & 15) * 4;
        float acc[4][4];
        #pragma unroll
        for (int pp = 0; pp < 4; ++pp)
            #pragma unroll
            for (int j = 0; j < 4; ++j) acc[pp][j] = 0.0f;

        const float* __restrict__ Wc = W + (size_t)c * DOUT * DIN;
        #pragma unroll 4
        for (int dd = 0; dd < DIN; dd += 4) {
            float4 w[4];
            #pragma unroll
            for (int j = 0; j < 4; ++j)
                w[j] = *(const float4*)(Wc + (size_t)(o0 + j) * DIN + dd);
            #pragma unroll
            for (int pp = 0; pp < 4; ++pp) {
                const int p = ph * 4 + pp;
                const float4 m = *(const float4*)(&mean_s[(p * CC + c) * MPAD + dd]);
                #pragma unroll
                for (int j = 0; j < 4; ++j) {
                    acc[pp][j] = fmaf(m.x, w[j].x, acc[pp][j]);
                    acc[pp][j] = fmaf(m.y, w[j].y, acc[pp][j]);
                    acc[pp][j] = fmaf(m.z, w[j].z, acc[pp][j]);
                    acc[pp][j] = fmaf(m.w, w[j].w, acc[pp][j]);
                }
            }
        }

        #pragma unroll
        for (int pp = 0; pp < 4; ++pp) {
            const int p = ph * 4 + pp;
            const int n = n0 + p;
            if (n < NN) {
                float4 r;
                r.x = fast_tanh(acc[pp][0]);
                r.y = fast_tanh(acc[pp][1]);
                r.z = fast_tanh(acc[pp][2]);
                r.w = fast_tanh(acc[pp][3]);
                *(float4*)(out + (((size_t)(b * NN + n)) * CC + c) * DOUT + o0) = r;
            }
        }
    }
}

extern "C" void kernel_launch(void* const* d_in, const int* in_sizes, int n_in,
                              void* d_out, int out_size, void* d_ws, size_t ws_size,
                              hipStream_t stream) {
    const int*   idx = (const int*)d_in[0];    // clustered_index_topk [B,N,K] int32
    const float* x   = (const float*)d_in[1];  // weightedDinput_topk [B,N,K,DIN] f32
    const float* W   = (const float*)d_in[2];  // W [C,DOUT,DIN] f32
    float* out = (float*)d_out;                // [B,N,C,DOUT] f32

    dim3 grid(NT, BB);   // 26 x 64 = 1664 blocks
    dim3 block(256);
    ordered_gcn_kernel<<<grid, block, 0, stream>>>(idx, x, W, out);
}